// Round 4
// baseline (393.928 us; speedup 1.0000x reference)
//
#include <hip/hip_runtime.h>

#define NN 50000
#define EE 800000
#define RR 8
#define DD 128
#define SS (NN*RR)        // 400000 segments
#define TE (2*EE)         // 1600000 directed edges
#define NB 782            // dst buckets of 64 nodes
#define NBLK 391          // partition blocks, 4096 directed edges each
#define NS (NB*NBLK)      // 305762 scan elements

typedef __attribute__((ext_vector_type(8))) short bf16x8;
typedef __attribute__((ext_vector_type(4))) float f32x4;

__device__ __forceinline__ unsigned short f2bf(float f){
  unsigned int u = __float_as_uint(f);
  u += 0x7fffu + ((u >> 16) & 1u);   // round-to-nearest-even
  return (unsigned short)(u >> 16);
}

// directed edge j in [0,TE): j<EE forward (s->d), else reversed
__device__ __forceinline__ void dir_edge(const int* ei, const int* et, int j,
                                         int& s, int& d, int& t){
  if (j < EE){ s = ei[j]; d = ei[EE + j]; t = et[j]; }
  else { int jj = j - EE; s = ei[EE + jj]; d = ei[jj]; t = et[jj]; }
}

// ---- partition phase A1: per-(bucket,block) histogram ---------------------
__global__ __launch_bounds__(256) void k_hist(const int* __restrict__ ei,
                                              const int* __restrict__ et,
                                              int* __restrict__ hist){
  __shared__ int h[NB];
  int tid = threadIdx.x, bid = blockIdx.x;
  for (int i = tid; i < NB; i += 256) h[i] = 0;
  __syncthreads();
  int j0 = bid*4096;
  for (int k = tid; k < 4096; k += 256){
    int j = j0 + k;
    if (j < TE){
      int s, d, t; dir_edge(ei, et, j, s, d, t);
      atomicAdd(&h[d >> 6], 1);           // LDS atomic
    }
  }
  __syncthreads();
  for (int i = tid; i < NB; i += 256) hist[i*NBLK + bid] = h[i];
}

// ---- scan over NS elements (in-place exclusive), 3 kernels ----------------
__global__ __launch_bounds__(256) void k_scan1(int* __restrict__ hist,
                                               int* __restrict__ blksum){
  __shared__ int sd[256];
  int b = blockIdx.x, tid = threadIdx.x;
  int base = b*1024 + tid*4;
  int v0 = (base+0 < NS) ? hist[base+0] : 0;
  int v1 = (base+1 < NS) ? hist[base+1] : 0;
  int v2 = (base+2 < NS) ? hist[base+2] : 0;
  int v3 = (base+3 < NS) ? hist[base+3] : 0;
  int ts = v0+v1+v2+v3;
  sd[tid] = ts; __syncthreads();
  for (int o = 1; o < 256; o <<= 1){
    int t = (tid >= o) ? sd[tid-o] : 0;
    __syncthreads();
    sd[tid] += t;
    __syncthreads();
  }
  int ex = sd[tid] - ts;
  if (base+0 < NS) hist[base+0] = ex; ex += v0;
  if (base+1 < NS) hist[base+1] = ex; ex += v1;
  if (base+2 < NS) hist[base+2] = ex; ex += v2;
  if (base+3 < NS) hist[base+3] = ex;
  if (tid == 255) blksum[b] = sd[255];
}

__global__ __launch_bounds__(512) void k_scan2(int* __restrict__ blksum, int nb){
  __shared__ int sd[512];
  int tid = threadIdx.x;
  int v = (tid < nb) ? blksum[tid] : 0;
  sd[tid] = v; __syncthreads();
  for (int o = 1; o < 512; o <<= 1){
    int t = (tid >= o) ? sd[tid-o] : 0;
    __syncthreads();
    sd[tid] += t;
    __syncthreads();
  }
  if (tid < nb) blksum[tid] = sd[tid] - v;   // exclusive
}

__global__ __launch_bounds__(256) void k_scan3(int* __restrict__ hist,
                                               const int* __restrict__ blksum){
  int i = blockIdx.x*blockDim.x + threadIdx.x;
  if (i < NS) hist[i] += blksum[i >> 10];
}

// ---- partition phase A3: place packed edges into bucket slices ------------
// packed: src (17b) | dstlo (6b @17) | rel (3b @23)
__global__ __launch_bounds__(256) void k_part(const int* __restrict__ ei,
                                              const int* __restrict__ et,
                                              const int* __restrict__ S,
                                              unsigned int* __restrict__ P){
  __shared__ int cur[NB];
  int tid = threadIdx.x, bid = blockIdx.x;
  for (int i = tid; i < NB; i += 256) cur[i] = S[i*NBLK + bid];
  __syncthreads();
  int j0 = bid*4096;
  for (int k = tid; k < 4096; k += 256){
    int j = j0 + k;
    if (j < TE){
      int s, d, t; dir_edge(ei, et, j, s, d, t);
      int b = d >> 6;
      int p = atomicAdd(&cur[b], 1);       // LDS atomic rank
      P[p] = (unsigned int)s | ((unsigned int)(d & 63) << 17)
           | ((unsigned int)t << 23);
    }
  }
}

// ---- phase B: per-bucket counting sort -> offs + esrc ---------------------
__global__ __launch_bounds__(256) void k_build(const unsigned int* __restrict__ P,
                                               const int* __restrict__ S,
                                               int* __restrict__ esrc,
                                               int* __restrict__ offs){
  __shared__ int h[512], cu[512], sd[256];
  int tid = threadIdx.x, b = blockIdx.x;
  int pstart = S[b*NBLK];
  int pend   = (b+1 < NB) ? S[(b+1)*NBLK] : TE;
  int ne = pend - pstart;
  h[2*tid] = 0; h[2*tid+1] = 0;
  __syncthreads();
  for (int k = tid; k < ne; k += 256){
    unsigned int u = P[pstart + k];
    int lseg = (int)(((u >> 17) & 63u)*8u + (u >> 23));
    atomicAdd(&h[lseg], 1);                // LDS atomic
  }
  __syncthreads();
  // exclusive scan of 512 bins with 256 threads
  int v0 = h[2*tid], v1 = h[2*tid+1];
  int ts = v0 + v1;
  sd[tid] = ts; __syncthreads();
  for (int o = 1; o < 256; o <<= 1){
    int t = (tid >= o) ? sd[tid-o] : 0;
    __syncthreads();
    sd[tid] += t;
    __syncthreads();
  }
  int ex = sd[tid] - ts;
  cu[2*tid]   = pstart + ex;
  cu[2*tid+1] = pstart + ex + v0;
  int seg0 = b*512;
  if (seg0 + 2*tid     < SS) offs[seg0 + 2*tid]     = cu[2*tid];
  if (seg0 + 2*tid + 1 < SS) offs[seg0 + 2*tid + 1] = cu[2*tid+1];
  if (b == NB-1 && tid == 0) offs[SS] = TE;
  __syncthreads();
  for (int k = tid; k < ne; k += 256){
    unsigned int u = P[pstart + k];
    int lseg = (int)(((u >> 17) & 63u)*8u + (u >> 23));
    int r = atomicAdd(&cu[lseg], 1);       // LDS atomic
    esrc[r] = (int)(u & 0x1ffffu);
  }
}

// ---- merged conversions: x->bf16, W/self_W -> bf16 transposed -------------
// Also zero-fills xb row NN (the "zero row" that dead edge-slots point at).
__global__ __launch_bounds__(256) void k_conv(const float* __restrict__ x,
                                              const float* __restrict__ w,
                                              const float* __restrict__ sw,
                                              unsigned short* __restrict__ xb,
                                              unsigned short* __restrict__ wb){
  int i = blockIdx.x*blockDim.x + threadIdx.x;
  const int M1 = NN*DD/4;            // 1,600,000 float4 groups
  if (i < M1){
    float4 v = ((const float4*)x)[i];
    ushort4 o;
    o.x = f2bf(v.x); o.y = f2bf(v.y); o.z = f2bf(v.z); o.w = f2bf(v.w);
    ((ushort4*)xb)[i] = o;
  } else {
    int j = i - M1;
    if (j < 9*DD*DD){
      int r = j >> 14; int rem = j & 16383; int n = rem >> 7; int k = rem & 127;
      float v = (r < 8) ? w[r*16384 + k*128 + n] : sw[k*128 + n];
      wb[j] = f2bf(v);
    } else if (j < 9*DD*DD + 32){
      ushort4 z; z.x = 0; z.y = 0; z.z = 0; z.w = 0;
      ((ushort4*)(xb + (size_t)NN*DD))[j - 9*DD*DD] = z;   // zero row
    }
  }
}

// ---- counted-vmcnt waits (T4). memory clobber + sched_barrier (rule 18) ---
#define WAITV(n) do { \
    asm volatile("s_waitcnt vmcnt(" #n ")" ::: "memory"); \
    __builtin_amdgcn_sched_barrier(0); \
  } while (0)

// ---- fused gather-as-MFMA kernel ------------------------------------------
// One WAVE owns 16 dst rows x all 128 out cols. NO __syncthreads anywhere.
// Per relation r: hold B (128x128 bf16) in 128 VGPRs; aggregate via MFMA
// "edge layers": layer k's A[m,:] = xb[ esrc[offs[m,r]+k] ] (zero row if
// k >= deg). Layers staged global->LDS with global_load_lds (per-lane global
// addr, linear LDS dest), depth-3 ring of 4 slots, counted vmcnt waits.
// A-reads XOR-swizzled (chunk ^= row&7) via pre-swizzled global source (m173).
// C_total += (1/deg) * C_r per relation; self-loop = one extra layer, scale 1.
__global__ __launch_bounds__(256, 2) void k_fused(
    const unsigned short* __restrict__ xb,
    const unsigned short* __restrict__ wb,
    const int* __restrict__ offs,
    const int* __restrict__ esrc,
    float* __restrict__ out)
{
  __shared__ __align__(16) unsigned short A[4][4][2048]; // [wave][slot][16*128] = 64 KiB
  const int tid  = threadIdx.x;
  const int wave = tid >> 6, lane = tid & 63;
  const int l15  = lane & 15, quad = lane >> 4;
  const int srow = lane >> 4;     // staging: row-within-group-of-4
  const int scol = lane & 15;     // staging: 16B chunk index within row
  const int row0 = blockIdx.x * 64 + wave * 16;

  // ---- hoisted CSR: voff0/vcnt0 rows 0-7, voff1/vcnt1 rows 8-15 ----------
  // lane L holds seg (row (L>>3), rel L&7) of its half
  int voff0 = 0, vcnt0 = 0, voff1 = 0, vcnt1 = 0;
  {
    int s0 = row0 * 8 + lane;
    if (s0 < SS){ voff0 = offs[s0]; vcnt0 = offs[s0 + 1] - voff0; }
    int s1 = (row0 + 8) * 8 + lane;
    if (s1 < SS){ voff1 = offs[s1]; vcnt1 = offs[s1 + 1] - voff1; }
  }
  float icnt0 = (vcnt0 > 0) ? 1.0f / (float)vcnt0 : 0.0f;
  float icnt1 = (vcnt1 > 0) ? 1.0f / (float)vcnt1 : 0.0f;

  // ---- per-rel max degree: fold row bits (3..5); lane L -> Lmax[rel L&7] --
  int redm;
  {
    int r0 = vcnt0, r1 = vcnt1;
    r0 = max(r0, __shfl_xor(r0, 8));  r1 = max(r1, __shfl_xor(r1, 8));
    r0 = max(r0, __shfl_xor(r0, 16)); r1 = max(r1, __shfl_xor(r1, 16));
    r0 = max(r0, __shfl_xor(r0, 32)); r1 = max(r1, __shfl_xor(r1, 32));
    redm = max(r0, r1);
  }

  f32x4 Ct[8];
  #pragma unroll
  for (int nt = 0; nt < 8; ++nt) Ct[nt] = (f32x4)(0.f);

  // stage one 16-row layer into slot: 4 calls x (64 lanes x 16B) = 4 KiB.
  // Global source pre-swizzled (chunk ^ row&7); LDS dest linear.
  auto stage = [&](int slot, int kk, int idreg){
    char* lbase = (char*)&A[wave][slot][0];
    #pragma unroll
    for (int j = 0; j < 4; ++j){
      int m  = 4 * j + srow;
      int id = __shfl(idreg, (m << 2) | (kk & 3));
      int cs = scol ^ (m & 7);
      const unsigned short* gp = xb + (size_t)id * DD + cs * 8;
      __builtin_amdgcn_global_load_lds(
          (const __attribute__((address_space(1))) void*)gp,
          (__attribute__((address_space(3))) void*)(lbase + j * 1024),
          16, 0, 0);
    }
  };

  #pragma unroll 1
  for (int r = 0; r < 8; ++r){
    // (a) idbuf FIRST (so the compiler's wait for it leaves later loads live):
    // idbuf[c] at lane L = src id of (seg L>>2, slot (L&3)+4c), or NN (zero row)
    int idbuf[4];
    {
      int m    = lane >> 2;
      int srcl = ((m & 7) << 3) | r;
      int oA = __shfl(voff0, srcl), oB = __shfl(voff1, srcl);
      int cA = __shfl(vcnt0, srcl), cB = __shfl(vcnt1, srcl);
      int off = (lane < 32) ? oA : oB;
      int cnt = (lane < 32) ? cA : cB;
      #pragma unroll
      for (int c = 0; c < 4; ++c){
        int sl = (lane & 3) + 4 * c;
        idbuf[c] = (sl < cnt) ? esrc[off + sl] : NN;
      }
    }

    // (b) B fragments for this relation: 128 VGPRs, loaded once, reused L times
    const unsigned short* wr = wb + r * 16384;
    bf16x8 bfrag[8][4];
    #pragma unroll
    for (int nt = 0; nt < 8; ++nt)
      #pragma unroll
      for (int ks = 0; ks < 4; ++ks)
        bfrag[nt][ks] = *(const bf16x8*)(wr + (nt*16 + l15)*128 + ks*32 + quad*8);

    int L = __shfl(redm, r);   // wave-uniform max degree for this rel

    // (c) prologue: stage layers 0..2
    if (L > 0) stage(0, 0, idbuf[0]);
    if (L > 1) stage(1, 1, idbuf[0]);
    if (L > 2) stage(2, 2, idbuf[0]);

    f32x4 Cr[8];
    #pragma unroll
    for (int nt = 0; nt < 8; ++nt) Cr[nt] = (f32x4)(0.f);

    // (d) layer loop: wait(counted) -> stage k+3 -> ds_read -> 32 MFMA
    #pragma unroll
    for (int k = 0; k < 16; ++k){
      if (k < L){
        if (k + 3 <= L)      { WAITV(8); }
        else if (k + 2 == L) { WAITV(4); }
        else                 { WAITV(0); }
        if (k + 3 < L) stage((k + 3) & 3, k + 3, idbuf[(k + 3) >> 2]);
        const char* abase = (const char*)&A[wave][k & 3][0];
        #pragma unroll
        for (int ks = 0; ks < 4; ++ks){
          int cb = ((ks * 32 + quad * 8) * 2) ^ ((l15 & 7) << 4);
          bf16x8 af = *(const bf16x8*)(abase + l15 * 256 + cb);
          #pragma unroll
          for (int nt = 0; nt < 8; ++nt)
            Cr[nt] = __builtin_amdgcn_mfma_f32_16x16x32_bf16(af, bfrag[nt][ks], Cr[nt], 0, 0, 0);
        }
      }
    }

    // (e) ultra-rare tail: segments with degree > 16 (serial, correct)
    if (L > 16){
      for (int k = 16; k < L; ++k){
        #pragma unroll
        for (int j = 0; j < 4; ++j){
          int m    = 4 * j + srow;
          int srcl = ((m & 7) << 3) | r;
          int oA = __shfl(voff0, srcl), oB = __shfl(voff1, srcl);
          int cA = __shfl(vcnt0, srcl), cB = __shfl(vcnt1, srcl);
          int off = (j < 2) ? oA : oB;      // j<2 <=> m<8 (static per j)
          int cnt = (j < 2) ? cA : cB;
          int id  = (k < cnt) ? esrc[off + k] : NN;
          int cs  = scol ^ (m & 7);
          const unsigned short* gp = xb + (size_t)id * DD + cs * 8;
          __builtin_amdgcn_global_load_lds(
              (const __attribute__((address_space(1))) void*)gp,
              (__attribute__((address_space(3))) void*)((char*)&A[wave][0][0] + j * 1024),
              16, 0, 0);
        }
        WAITV(0);
        const char* abase = (const char*)&A[wave][0][0];
        #pragma unroll
        for (int ks = 0; ks < 4; ++ks){
          int cb = ((ks * 32 + quad * 8) * 2) ^ ((l15 & 7) << 4);
          bf16x8 af = *(const bf16x8*)(abase + l15 * 256 + cb);
          #pragma unroll
          for (int nt = 0; nt < 8; ++nt)
            Cr[nt] = __builtin_amdgcn_mfma_f32_16x16x32_bf16(af, bfrag[nt][ks], Cr[nt], 0, 0, 0);
        }
      }
    }

    // (f) scale by 1/deg per row and accumulate
    #pragma unroll
    for (int i = 0; i < 4; ++i){
      int srcl = ((((quad & 1) * 4) + i) << 3) | r;   // (row&7, rel r)
      float sA = __shfl(icnt0, srcl);
      float sB = __shfl(icnt1, srcl);
      float s  = (quad < 2) ? sA : sB;
      #pragma unroll
      for (int nt = 0; nt < 8; ++nt)
        Ct[nt][i] += s * Cr[nt][i];
    }
  }

  // ---- self loop: one layer, A = own rows, scale 1 ------------------------
  {
    const unsigned short* wr = wb + 8 * 16384;
    bf16x8 bfrag[8][4];
    #pragma unroll
    for (int nt = 0; nt < 8; ++nt)
      #pragma unroll
      for (int ks = 0; ks < 4; ++ks)
        bfrag[nt][ks] = *(const bf16x8*)(wr + (nt*16 + l15)*128 + ks*32 + quad*8);
    #pragma unroll
    for (int j = 0; j < 4; ++j){
      int m  = 4 * j + srow;
      int gd = row0 + m;
      int id = (gd < NN) ? gd : NN;
      int cs = scol ^ (m & 7);
      const unsigned short* gp = xb + (size_t)id * DD + cs * 8;
      __builtin_amdgcn_global_load_lds(
          (const __attribute__((address_space(1))) void*)gp,
          (__attribute__((address_space(3))) void*)((char*)&A[wave][0][0] + j * 1024),
          16, 0, 0);
    }
    WAITV(0);
    const char* abase = (const char*)&A[wave][0][0];
    #pragma unroll
    for (int ks = 0; ks < 4; ++ks){
      int cb = ((ks * 32 + quad * 8) * 2) ^ ((l15 & 7) << 4);
      bf16x8 af = *(const bf16x8*)(abase + l15 * 256 + cb);
      #pragma unroll
      for (int nt = 0; nt < 8; ++nt)
        Ct[nt] = __builtin_amdgcn_mfma_f32_16x16x32_bf16(af, bfrag[nt][ks], Ct[nt], 0, 0, 0);
    }
  }

  // ---- store: C elem (nt,i) -> out[row0 + quad*4 + i][nt*16 + l15] --------
  #pragma unroll
  for (int nt = 0; nt < 8; ++nt){
    #pragma unroll
    for (int i = 0; i < 4; ++i){
      int gr = row0 + quad * 4 + i;
      if (gr < NN) out[(size_t)gr * DD + nt * 16 + l15] = Ct[nt][i];
    }
  }
}

// ---- workspace layout (bytes) ---------------------------------------------
// xb     @ 0          : (NN+1)*DD*2 = 12,800,256  (row NN = zero row)
//   (aliased during partition: hist @ 0 (1,223,168), blksum @ 1,223,168
//    (2,048), P @ 1,225,216 (6,400,000) — all dead before k_conv writes xb)
// esrc   @ 12,800,256 : TE*4    = 6,400,000
// offs   @ 19,200,256 : (SS+1)*4 -> 1,600,016
// wb     @ 20,800,272 : 9*DD*DD*2 = 294,912
// total 21,095,184
extern "C" void kernel_launch(void* const* d_in, const int* in_sizes, int n_in,
                              void* d_out, int out_size, void* d_ws, size_t ws_size,
                              hipStream_t stream){
  const float* x  = (const float*)d_in[0];
  const float* w  = (const float*)d_in[1];
  const float* sw = (const float*)d_in[2];
  const int*   ei = (const int*)d_in[3];
  const int*   et = (const int*)d_in[4];
  float* out = (float*)d_out;
  char* ws = (char*)d_ws;

  if (ws_size < (size_t)21100000) return;

  unsigned short* xb = (unsigned short*)(ws + 0);
  int*          hist = (int*)(ws + 0);               // alias (dead before xb)
  int*        blksum = (int*)(ws + 1223168);         // alias
  unsigned int*    P = (unsigned int*)(ws + 1225216);// alias
  int*          esrc = (int*)(ws + 12800256);
  int*          offs = (int*)(ws + 19200256);
  unsigned short* wb = (unsigned short*)(ws + 20800272);

  k_hist <<<NBLK, 256, 0, stream>>>(ei, et, hist);
  k_scan1<<<(NS + 1023)/1024, 256, 0, stream>>>(hist, blksum);   // 299 blocks
  k_scan2<<<1, 512, 0, stream>>>(blksum, (NS + 1023)/1024);
  k_scan3<<<(NS + 255)/256, 256, 0, stream>>>(hist, blksum);
  k_part <<<NBLK, 256, 0, stream>>>(ei, et, hist, P);
  k_build<<<NB, 256, 0, stream>>>(P, hist, esrc, offs);
  k_conv <<<(NN*DD/4 + 9*DD*DD + 32 + 255)/256, 256, 0, stream>>>(x, w, sw, xb, wb);
  k_fused<<<(NN + 63)/64, 256, 0, stream>>>(xb, wb, offs, esrc, out);
}

// Round 5
// 359.278 us; speedup vs baseline: 1.0964x; 1.0964x over previous
//
#include <hip/hip_runtime.h>

#define NN 50000
#define EE 800000
#define RR 8
#define DD 128
#define SS (NN*RR)        // 400000 segments
#define TE (2*EE)         // 1600000 directed edges
#define NB 782            // dst buckets of 64 nodes
#define NBLK 391          // partition blocks, 4096 directed edges each
#define NS (NB*NBLK)      // 305762 scan elements

typedef __attribute__((ext_vector_type(8))) short bf16x8;
typedef __attribute__((ext_vector_type(4))) float f32x4;

__device__ __forceinline__ unsigned short f2bf(float f){
  unsigned int u = __float_as_uint(f);
  u += 0x7fffu + ((u >> 16) & 1u);   // round-to-nearest-even
  return (unsigned short)(u >> 16);
}
__device__ __forceinline__ float bf_lo(unsigned int w){ return __uint_as_float(w << 16); }
__device__ __forceinline__ float bf_hi(unsigned int w){ return __uint_as_float(w & 0xffff0000u); }

__device__ __forceinline__ void acc8(float* a, uint4 u){
  a[0] += bf_lo(u.x); a[1] += bf_hi(u.x);
  a[2] += bf_lo(u.y); a[3] += bf_hi(u.y);
  a[4] += bf_lo(u.z); a[5] += bf_hi(u.z);
  a[6] += bf_lo(u.w); a[7] += bf_hi(u.w);
}
__device__ __forceinline__ void acc8s(float* a, uint4 u, float s){
  a[0] += s*bf_lo(u.x); a[1] += s*bf_hi(u.x);
  a[2] += s*bf_lo(u.y); a[3] += s*bf_hi(u.y);
  a[4] += s*bf_lo(u.z); a[5] += s*bf_hi(u.z);
  a[6] += s*bf_lo(u.w); a[7] += s*bf_hi(u.w);
}
__device__ __forceinline__ unsigned int pack2(float a, float b){
  return ((unsigned int)f2bf(b) << 16) | (unsigned int)f2bf(a);
}

// directed edge j in [0,TE): j<EE forward (s->d), else reversed
__device__ __forceinline__ void dir_edge(const int* ei, const int* et, int j,
                                         int& s, int& d, int& t){
  if (j < EE){ s = ei[j]; d = ei[EE + j]; t = et[j]; }
  else { int jj = j - EE; s = ei[EE + jj]; d = ei[jj]; t = et[jj]; }
}

// ---- partition phase A1: per-(bucket,block) histogram ---------------------
__global__ __launch_bounds__(256) void k_hist(const int* __restrict__ ei,
                                              const int* __restrict__ et,
                                              int* __restrict__ hist){
  __shared__ int h[NB];
  int tid = threadIdx.x, bid = blockIdx.x;
  for (int i = tid; i < NB; i += 256) h[i] = 0;
  __syncthreads();
  int j0 = bid*4096;
  for (int k = tid; k < 4096; k += 256){
    int j = j0 + k;
    if (j < TE){
      int s, d, t; dir_edge(ei, et, j, s, d, t);
      atomicAdd(&h[d >> 6], 1);           // LDS atomic
    }
  }
  __syncthreads();
  for (int i = tid; i < NB; i += 256) hist[i*NBLK + bid] = h[i];
}

// ---- scan over NS elements (in-place exclusive), 3 kernels ----------------
__global__ __launch_bounds__(256) void k_scan1(int* __restrict__ hist,
                                               int* __restrict__ blksum){
  __shared__ int sd[256];
  int b = blockIdx.x, tid = threadIdx.x;
  int base = b*1024 + tid*4;
  int v0 = (base+0 < NS) ? hist[base+0] : 0;
  int v1 = (base+1 < NS) ? hist[base+1] : 0;
  int v2 = (base+2 < NS) ? hist[base+2] : 0;
  int v3 = (base+3 < NS) ? hist[base+3] : 0;
  int ts = v0+v1+v2+v3;
  sd[tid] = ts; __syncthreads();
  for (int o = 1; o < 256; o <<= 1){
    int t = (tid >= o) ? sd[tid-o] : 0;
    __syncthreads();
    sd[tid] += t;
    __syncthreads();
  }
  int ex = sd[tid] - ts;
  if (base+0 < NS) hist[base+0] = ex; ex += v0;
  if (base+1 < NS) hist[base+1] = ex; ex += v1;
  if (base+2 < NS) hist[base+2] = ex; ex += v2;
  if (base+3 < NS) hist[base+3] = ex;
  if (tid == 255) blksum[b] = sd[255];
}

__global__ __launch_bounds__(512) void k_scan2(int* __restrict__ blksum, int nb){
  __shared__ int sd[512];
  int tid = threadIdx.x;
  int v = (tid < nb) ? blksum[tid] : 0;
  sd[tid] = v; __syncthreads();
  for (int o = 1; o < 512; o <<= 1){
    int t = (tid >= o) ? sd[tid-o] : 0;
    __syncthreads();
    sd[tid] += t;
    __syncthreads();
  }
  if (tid < nb) blksum[tid] = sd[tid] - v;   // exclusive
}

__global__ __launch_bounds__(256) void k_scan3(int* __restrict__ hist,
                                               const int* __restrict__ blksum){
  int i = blockIdx.x*blockDim.x + threadIdx.x;
  if (i < NS) hist[i] += blksum[i >> 10];
}

// ---- partition phase A3: place packed edges into bucket slices ------------
// packed: src (17b) | dstlo (6b @17) | rel (3b @23)
__global__ __launch_bounds__(256) void k_part(const int* __restrict__ ei,
                                              const int* __restrict__ et,
                                              const int* __restrict__ S,
                                              unsigned int* __restrict__ P){
  __shared__ int cur[NB];
  int tid = threadIdx.x, bid = blockIdx.x;
  for (int i = tid; i < NB; i += 256) cur[i] = S[i*NBLK + bid];
  __syncthreads();
  int j0 = bid*4096;
  for (int k = tid; k < 4096; k += 256){
    int j = j0 + k;
    if (j < TE){
      int s, d, t; dir_edge(ei, et, j, s, d, t);
      int b = d >> 6;
      int p = atomicAdd(&cur[b], 1);       // LDS atomic rank
      P[p] = (unsigned int)s | ((unsigned int)(d & 63) << 17)
           | ((unsigned int)t << 23);
    }
  }
}

// ---- phase B: per-bucket counting sort -> offs + esrc ---------------------
// esrc entries are packed: src (17b) | rel (3b @17)
__global__ __launch_bounds__(256) void k_build(const unsigned int* __restrict__ P,
                                               const int* __restrict__ S,
                                               int* __restrict__ esrc,
                                               int* __restrict__ offs){
  __shared__ int h[512], cu[512], sd[256];
  int tid = threadIdx.x, b = blockIdx.x;
  int pstart = S[b*NBLK];
  int pend   = (b+1 < NB) ? S[(b+1)*NBLK] : TE;
  int ne = pend - pstart;
  h[2*tid] = 0; h[2*tid+1] = 0;
  __syncthreads();
  for (int k = tid; k < ne; k += 256){
    unsigned int u = P[pstart + k];
    int lseg = (int)(((u >> 17) & 63u)*8u + (u >> 23));
    atomicAdd(&h[lseg], 1);                // LDS atomic
  }
  __syncthreads();
  // exclusive scan of 512 bins with 256 threads
  int v0 = h[2*tid], v1 = h[2*tid+1];
  int ts = v0 + v1;
  sd[tid] = ts; __syncthreads();
  for (int o = 1; o < 256; o <<= 1){
    int t = (tid >= o) ? sd[tid-o] : 0;
    __syncthreads();
    sd[tid] += t;
    __syncthreads();
  }
  int ex = sd[tid] - ts;
  cu[2*tid]   = pstart + ex;
  cu[2*tid+1] = pstart + ex + v0;
  int seg0 = b*512;
  if (seg0 + 2*tid     < SS) offs[seg0 + 2*tid]     = cu[2*tid];
  if (seg0 + 2*tid + 1 < SS) offs[seg0 + 2*tid + 1] = cu[2*tid+1];
  if (b == NB-1 && tid == 0) offs[SS] = TE;
  __syncthreads();
  for (int k = tid; k < ne; k += 256){
    unsigned int u = P[pstart + k];
    int lseg = (int)(((u >> 17) & 63u)*8u + (u >> 23));
    int r = atomicAdd(&cu[lseg], 1);       // LDS atomic
    esrc[r] = (int)(u & 0x1ffffu) | (int)(((u >> 23) & 7u) << 17);
  }
}

// ---- merged conversions: x->bf16, W/self_W -> bf16 transposed -------------
__global__ __launch_bounds__(256) void k_conv(const float* __restrict__ x,
                                              const float* __restrict__ w,
                                              const float* __restrict__ sw,
                                              unsigned short* __restrict__ xb,
                                              unsigned short* __restrict__ wb){
  int i = blockIdx.x*blockDim.x + threadIdx.x;
  const int M1 = NN*DD/4;            // 1,600,000 float4 groups
  if (i < M1){
    float4 v = ((const float4*)x)[i];
    ushort4 o;
    o.x = f2bf(v.x); o.y = f2bf(v.y); o.z = f2bf(v.z); o.w = f2bf(v.w);
    ((ushort4*)xb)[i] = o;
  } else {
    int j = i - M1;
    if (j < 9*DD*DD){
      int r = j >> 14; int rem = j & 16383; int n = rem >> 7; int k = rem & 127;
      float v = (r < 8) ? w[r*16384 + k*128 + n] : sw[k*128 + n];
      wb[j] = f2bf(v);
    }
  }
}

// ===========================================================================
// BIG-WORKSPACE PATH: dense xw precompute + pure streaming aggregate
// ===========================================================================

// ---- k_xw: xw[r] = xb @ W_r for r=0..8 (slab 8 = self weight) -------------
// Block 256 = 4 waves; wave owns 16 rows x 128 cols. No LDS, no barriers:
// A-fragments loaded from global directly in MFMA layout, reused for 9 rels.
__global__ __launch_bounds__(256, 2) void k_xw(
    const unsigned short* __restrict__ xb,
    const unsigned short* __restrict__ wb,
    unsigned short* __restrict__ xw)
{
  const int tid  = threadIdx.x;
  const int wave = tid >> 6, lane = tid & 63;
  const int l15  = lane & 15, quad = lane >> 4;
  const int row0 = blockIdx.x * 64 + wave * 16;

  // A fragments: lane l15 = row, quad*8 + ks*32 = k. Loaded once, 9x reuse.
  bf16x8 af[4];
  {
    int gr = row0 + l15; if (gr >= NN) gr = NN - 1;
    #pragma unroll
    for (int ks = 0; ks < 4; ++ks)
      af[ks] = *(const bf16x8*)(xb + (size_t)gr*DD + ks*32 + quad*8);
  }

  #pragma unroll 1
  for (int r = 0; r < 9; ++r){
    const unsigned short* wr = wb + r * 16384;
    bf16x8 bfrag[8][4];
    #pragma unroll
    for (int nt = 0; nt < 8; ++nt)
      #pragma unroll
      for (int ks = 0; ks < 4; ++ks)
        bfrag[nt][ks] = *(const bf16x8*)(wr + (nt*16 + l15)*128 + ks*32 + quad*8);

    f32x4 C[8];
    #pragma unroll
    for (int nt = 0; nt < 8; ++nt) C[nt] = (f32x4)(0.f);
    #pragma unroll
    for (int ks = 0; ks < 4; ++ks)
      #pragma unroll
      for (int nt = 0; nt < 8; ++nt)
        C[nt] = __builtin_amdgcn_mfma_f32_16x16x32_bf16(af[ks], bfrag[nt][ks], C[nt], 0, 0, 0);

    unsigned short* xs = xw + (size_t)r * NN * DD;
    #pragma unroll
    for (int nt = 0; nt < 8; ++nt)
      #pragma unroll
      for (int i = 0; i < 4; ++i){
        int gr = row0 + quad*4 + i;
        if (gr < NN) xs[(size_t)gr*DD + nt*16 + l15] = f2bf(C[nt][i]);
      }
  }
}

// ---- k_agg: out[d] = sum_edges (1/deg_seg)*xw[rel][src] + xw[8][d] --------
// 16-lane group per dst node. Pure streaming: 12-deep masked load bursts,
// f32 accumulate, no LDS, no barriers, no MFMA.
__global__ __launch_bounds__(256, 4) void k_agg(
    const unsigned short* __restrict__ xw,
    const int* __restrict__ offs,
    const int* __restrict__ esrc,
    float* __restrict__ out)
{
  const int tid   = threadIdx.x;
  const int lane  = tid & 63;
  const int gl    = lane & 15;
  const int basel = lane & 48;               // group base lane within wave
  const int d     = blockIdx.x * 16 + (tid >> 4);   // NN = 3125*16 exact

  int o = 0;
  if (gl < 9) o = offs[d*8 + gl];
  int onx = __shfl(o, (basel + gl + 1) & 63);       // valid for gl<8
  int cnt = onx - o;
  float scale = (gl < 8 && cnt > 0) ? 1.0f/(float)cnt : 0.0f;
  int ebase = __shfl(o, basel);
  int etot  = __shfl(o, basel + 8) - ebase;

  float a[8] = {0.f,0.f,0.f,0.f,0.f,0.f,0.f,0.f};

  for (int e = 0; e < etot; e += 12){
    uint4 U[12]; float sc[12];
    #pragma unroll
    for (int s = 0; s < 12; ++s){
      sc[s] = 0.f;
      U[s] = make_uint4(0u,0u,0u,0u);
      if (e + s < etot){                     // group-uniform predicate
        int pk  = esrc[ebase + e + s];       // same addr across group: bcast
        int rel = (pk >> 17) & 7;
        sc[s]   = __shfl(scale, basel + rel);
        int src = pk & 0x1ffff;
        U[s] = *(const uint4*)(xw + ((size_t)rel*NN + src)*DD + gl*8);
      }
    }
    #pragma unroll
    for (int s = 0; s < 12; ++s) acc8s(a, U[s], sc[s]);
  }

  // self row (slab 8), scale 1
  {
    uint4 u = *(const uint4*)(xw + ((size_t)8*NN + d)*DD + gl*8);
    acc8(a, u);
  }

  float4 v0; v0.x = a[0]; v0.y = a[1]; v0.z = a[2]; v0.w = a[3];
  float4 v1; v1.x = a[4]; v1.y = a[5]; v1.z = a[6]; v1.w = a[7];
  *(float4*)(out + (size_t)d*DD + gl*8)     = v0;
  *(float4*)(out + (size_t)d*DD + gl*8 + 4) = v1;
}

// ===========================================================================
// FALLBACK PATH (small workspace): R3 fused kernel, patched for packed esrc
// ===========================================================================
__global__ __launch_bounds__(256, 3) void k_fused_fb(
    const unsigned short* __restrict__ xb,
    const unsigned short* __restrict__ wb,
    const int* __restrict__ offs,
    const int* __restrict__ esrc,
    float* __restrict__ out)
{
  __shared__ __align__(16) unsigned short Alds[2][32][136]; // +8 pad, 17,408 B
  const int tid  = threadIdx.x;
  const int wave = tid >> 6, lane = tid & 63;
  const int l15  = lane & 15, quad = lane >> 4;
  const int g    = quad;
  const int gl   = l15;
  const int lb   = g << 4;
  const int rowbase = blockIdx.x * 32;

  uint4 selfU[2];
  #pragma unroll
  for (int p = 0; p < 2; ++p){
    int gd = rowbase + wave*8 + 2*g + p;
    selfU[p] = make_uint4(0u,0u,0u,0u);
    if (gd < NN) selfU[p] = *(const uint4*)(xb + (size_t)gd*DD + gl*8);
  }

  int sidx = (rowbase + wave*8)*8 + lane;
  int voff = 0, vcnt = 0;
  if (sidx < SS){
    voff = offs[sidx];
    vcnt = offs[sidx + 1] - voff;
  }

  int idxbuf[2][2];
  uint4 U[2][8];

  auto issue_idx = [&](int rq, int bi){
    #pragma unroll
    for (int p = 0; p < 2; ++p){
      int sl  = (2*g + p)*8 + rq;
      int off = __shfl(voff, sl);
      int cnt = __shfl(vcnt, sl);
      idxbuf[bi][p] = 0;
      if (gl < cnt) idxbuf[bi][p] = esrc[off + gl];
    }
  };

  auto issue_bursts = [&](int rq, int bi){
    #pragma unroll
    for (int p = 0; p < 2; ++p){
      int sl  = (2*g + p)*8 + rq;
      int cnt = __shfl(vcnt, sl);
      int cm  = cnt < 8 ? cnt : 8;
      #pragma unroll
      for (int e = 0; e < 8; ++e){
        U[p][e] = make_uint4(0u,0u,0u,0u);
        if (e < cm){
          int s = __shfl(idxbuf[bi][p], lb + e) & 0x1ffff;
          U[p][e] = *(const uint4*)(xb + (size_t)s*DD + gl*8);
        }
      }
    }
  };

  auto finish = [&](int rq, int bi, int lbuf){
    #pragma unroll
    for (int p = 0; p < 2; ++p){
      int sl  = (2*g + p)*8 + rq;
      int cnt = __shfl(vcnt, sl);
      int off = __shfl(voff, sl);
      float a[8] = {0.f,0.f,0.f,0.f,0.f,0.f,0.f,0.f};
      #pragma unroll
      for (int e = 0; e < 8; ++e) acc8(a, U[p][e]);
      int cm16 = cnt < 16 ? cnt : 16;
      for (int e2 = 8; e2 < cm16; ++e2){
        int s = __shfl(idxbuf[bi][p], lb + e2) & 0x1ffff;
        uint4 u = *(const uint4*)(xb + (size_t)s*DD + gl*8);
        acc8(a, u);
      }
      for (int e2 = 16; e2 < cnt; ++e2){
        int s = esrc[off + e2] & 0x1ffff;
        uint4 u = *(const uint4*)(xb + (size_t)s*DD + gl*8);
        acc8(a, u);
      }
      float sc = (cnt > 0) ? (1.0f / (float)cnt) : 0.f;
      uint4 w0;
      w0.x = pack2(a[0]*sc, a[1]*sc);
      w0.y = pack2(a[2]*sc, a[3]*sc);
      w0.z = pack2(a[4]*sc, a[5]*sc);
      w0.w = pack2(a[6]*sc, a[7]*sc);
      int rowl = wave*8 + 2*g + p;
      *(uint4*)&Alds[lbuf][rowl][gl*8] = w0;
    }
  };

  issue_idx(0, 0);
  issue_idx(1, 1);
  issue_bursts(0, 0);
  finish(0, 0, 0);
  __syncthreads();

  f32x4 C[2][2];
  #pragma unroll
  for (int m = 0; m < 2; ++m){ C[m][0] = (f32x4)(0.f); C[m][1] = (f32x4)(0.f); }

  #pragma unroll
  for (int rr = 0; rr < 9; ++rr){
    const unsigned short* wr = wb + rr * 16384;
    bf16x8 bfrag[2][4];
    #pragma unroll
    for (int nt = 0; nt < 2; ++nt)
      #pragma unroll
      for (int ks = 0; ks < 4; ++ks)
        bfrag[nt][ks] = *(const bf16x8*)(wr + (wave*32 + nt*16 + l15)*128 + ks*32 + quad*8);

    if (rr < 7) issue_bursts(rr + 1, (rr + 1) & 1);
    if (rr <= 5) issue_idx(rr + 2, rr & 1);

    #pragma unroll
    for (int m = 0; m < 2; ++m){
      #pragma unroll
      for (int ks = 0; ks < 4; ++ks){
        bf16x8 af = *(const bf16x8*)&Alds[rr & 1][m*16 + l15][ks*32 + quad*8];
        C[m][0] = __builtin_amdgcn_mfma_f32_16x16x32_bf16(af, bfrag[0][ks], C[m][0], 0, 0, 0);
        C[m][1] = __builtin_amdgcn_mfma_f32_16x16x32_bf16(af, bfrag[1][ks], C[m][1], 0, 0, 0);
      }
    }

    if (rr < 7) finish(rr + 1, (rr + 1) & 1, (rr + 1) & 1);
    if (rr == 7){
      #pragma unroll
      for (int p = 0; p < 2; ++p){
        int rowl = wave*8 + 2*g + p;
        *(uint4*)&Alds[0][rowl][gl*8] = selfU[p];
      }
    }
    if (rr < 8) __syncthreads();
  }

  #pragma unroll
  for (int m = 0; m < 2; ++m){
    #pragma unroll
    for (int nt = 0; nt < 2; ++nt){
      #pragma unroll
      for (int i = 0; i < 4; ++i){
        int row = m*16 + quad*4 + i;
        int gd  = rowbase + row;
        int col = wave*32 + nt*16 + l15;
        if (gd < NN) out[gd*DD + col] = C[m][nt][i];
      }
    }
  }
}

// ---- workspace layout (bytes) ---------------------------------------------
// xb     @ 0          : NN*DD*2 = 12,800,000
//   (aliased during partition: hist @ 0 (1,223,168), blksum @ 1,223,168
//    (2,048), P @ 1,225,216 (6,400,000) — all dead before k_conv writes xb)
// esrc   @ 12,800,000 : TE*4    = 6,400,000
// offs   @ 19,200,000 : (SS+1)*4 -> 1,600,016
// wb     @ 20,800,016 : 9*DD*DD*2 = 294,912        -> end 21,094,928
// xw     @ 21,095,168 : 9*NN*DD*2 = 115,200,000    -> end 136,295,168 (big path)
extern "C" void kernel_launch(void* const* d_in, const int* in_sizes, int n_in,
                              void* d_out, int out_size, void* d_ws, size_t ws_size,
                              hipStream_t stream){
  const float* x  = (const float*)d_in[0];
  const float* w  = (const float*)d_in[1];
  const float* sw = (const float*)d_in[2];
  const int*   ei = (const int*)d_in[3];
  const int*   et = (const int*)d_in[4];
  float* out = (float*)d_out;
  char* ws = (char*)d_ws;

  if (ws_size < (size_t)21100000) return;

  unsigned short* xb = (unsigned short*)(ws + 0);
  int*          hist = (int*)(ws + 0);               // alias (dead before xb)
  int*        blksum = (int*)(ws + 1223168);         // alias
  unsigned int*    P = (unsigned int*)(ws + 1225216);// alias
  int*          esrc = (int*)(ws + 12800000);
  int*          offs = (int*)(ws + 19200000);
  unsigned short* wb = (unsigned short*)(ws + 20800016);
  unsigned short* xw = (unsigned short*)(ws + 21095168);

  k_hist <<<NBLK, 256, 0, stream>>>(ei, et, hist);
  k_scan1<<<(NS + 1023)/1024, 256, 0, stream>>>(hist, blksum);   // 299 blocks
  k_scan2<<<1, 512, 0, stream>>>(blksum, (NS + 1023)/1024);
  k_scan3<<<(NS + 255)/256, 256, 0, stream>>>(hist, blksum);
  k_part <<<NBLK, 256, 0, stream>>>(ei, et, hist, P);
  k_build<<<NB, 256, 0, stream>>>(P, hist, esrc, offs);
  k_conv <<<(NN*DD/4 + 9*DD*DD + 255)/256, 256, 0, stream>>>(x, w, sw, xb, wb);

  if (ws_size >= (size_t)136295168){
    k_xw <<<(NN + 63)/64, 256, 0, stream>>>(xb, wb, xw);
    k_agg<<<NN/16, 256, 0, stream>>>(xw, offs, esrc, out);
  } else {
    k_fused_fb<<<(NN + 31)/32, 256, 0, stream>>>(xb, wb, offs, esrc, out);
  }
}